// Round 10
// baseline (140.637 us; speedup 1.0000x reference)
//
// Round 10 = retry of round 9 (infra failure, never executed): non-temporal
// loads/stores on all touch-once streams; out_h transpose merged into pred.
#include <hip/hip_runtime.h>
#include <math.h>

namespace {

constexpr int B     = 512;
constexpr int IN    = 2048;
constexpr int HID   = 4096;
constexpr int NNZ_W = 83886;
constexpr int NNZ_R = 167772;
constexpr int NTOT  = NNZ_W + 2 * NNZ_R;   // 419430 edges across W,R,P
constexpr int NCOLS = 3 * HID;             // global column id = mat*HID + col
constexpr int SLOT  = 128;                 // per-column bucket capacity
constexpr float DT  = 0.1f;

typedef float f4 __attribute__((ext_vector_type(4)));
typedef float f2 __attribute__((ext_vector_type(2)));

struct ushort4_t { unsigned short x, y, z, w; };

__device__ __forceinline__ float bf2f(unsigned short u) {
  return __uint_as_float((unsigned int)u << 16);
}
__device__ __forceinline__ unsigned short f2bf(float f) {  // round-nearest-even
  unsigned int u = __float_as_uint(f);
  u += 0x7FFFu + ((u >> 16) & 1u);
  return (unsigned short)(u >> 16);
}

// ---------------------------------------------------------------------------
// prep_k, 512 threads, multi-role by blockIdx.x:
//  [0,256)    transpose x[B][IN]  -> xTb (bf16) [IN][B]          (cached store)
//  [256,768)  transpose h[B][HID] -> hT (f32, nt) + hTb (bf16)   (h read nt)
//  [768,896)  router: 4 batch rows per block, wave-per-output
//  [896,920)  zero cnt[NCOLS]
// ---------------------------------------------------------------------------
__global__ void prep_k(const float* __restrict__ x, unsigned short* __restrict__ xTb,
                       const float* __restrict__ h, float* __restrict__ hT,
                       unsigned short* __restrict__ hTb,
                       const float* __restrict__ rw, const float* __restrict__ rb,
                       float* __restrict__ rgT, int* __restrict__ cnt) {
  __shared__ float sh[4 * IN];            // 32 KB; transpose uses first 4160
  const int blk = blockIdx.x;
  const int tid = threadIdx.x;

  if (blk < 768) {                        // --- transpose roles ---
    const bool isX = blk < 256;
    const float* src; int C, tb;
    if (isX) { src = x; C = IN;  tb = blk; }
    else     { src = h; C = HID; tb = blk - 256; }
    const int tx_n = C / 64;
    const int bx = (tb % tx_n) * 64;
    const int by = (tb / tx_n) * 64;
    const int tx = tid & 63;
    const int ty = tid >> 6;              // 0..7
    for (int i = ty; i < 64; i += 8)
      sh[i * 65 + tx] = __builtin_nontemporal_load(&src[(size_t)(by + i) * C + bx + tx]);
    __syncthreads();
    for (int i = ty; i < 64; i += 8) {
      const float v = sh[tx * 65 + i];
      const size_t di = (size_t)(bx + i) * B + by + tx;
      if (isX) xTb[di] = f2bf(v);         // cached: hot gather source
      else     { __builtin_nontemporal_store(v, &hT[di]); hTb[di] = f2bf(v); }
    }
  } else if (blk < 896) {                 // --- router: 4 b-rows per block ---
    const int b0 = (blk - 768) * 4;
    for (int k = tid; k < 4 * IN; k += 512) sh[k] = x[(size_t)b0 * IN + k];
    __syncthreads();
    const int wave = tid >> 6;
    const int lane = tid & 63;
#pragma unroll
    for (int j = 0; j < 8; ++j) {
      const int o = wave * 8 + j;
      const float* w = rw + (size_t)o * IN;
      float s0 = 0.f, s1 = 0.f, s2 = 0.f, s3 = 0.f;
      for (int i = 0; i < IN / 64; ++i) {           // 32 iters
        const float wv = w[lane + 64 * i];          // coalesced 256B
        s0 += sh[0 * IN + lane + 64 * i] * wv;
        s1 += sh[1 * IN + lane + 64 * i] * wv;
        s2 += sh[2 * IN + lane + 64 * i] * wv;
        s3 += sh[3 * IN + lane + 64 * i] * wv;
      }
#pragma unroll
      for (int d = 1; d < 64; d <<= 1) {
        s0 += __shfl_xor(s0, d);
        s1 += __shfl_xor(s1, d);
        s2 += __shfl_xor(s2, d);
        s3 += __shfl_xor(s3, d);
      }
      if (lane == 0) {
        const float bias = rb[o];
        rgT[o * B + b0 + 0] = 1.f / (1.f + expf(-(s0 + bias)));
        rgT[o * B + b0 + 1] = 1.f / (1.f + expf(-(s1 + bias)));
        rgT[o * B + b0 + 2] = 1.f / (1.f + expf(-(s2 + bias)));
        rgT[o * B + b0 + 3] = 1.f / (1.f + expf(-(s3 + bias)));
      }
    }
  } else {                                // --- zero cnt ---
    const int i = (blk - 896) * 512 + tid;
    if (i < NCOLS) cnt[i] = 0;
  }
}

// ---------------------------------------------------------------------------
// One-kernel binning: edge -> (global col bucket, atomic slot).
// Touch-once data: nt reads of edge lists, nt write of packed.
// ---------------------------------------------------------------------------
__global__ void slotscat_k(const int* __restrict__ Wc, const int* __restrict__ Rc,
                           const int* __restrict__ Pc, const int* __restrict__ Wr,
                           const int* __restrict__ Rr, const int* __restrict__ Pr,
                           const float* __restrict__ Wv, const float* __restrict__ Rv,
                           const float* __restrict__ Pv, int* __restrict__ cnt,
                           float2* __restrict__ packed) {
  const int i = blockIdx.x * blockDim.x + threadIdx.x;
  if (i >= NTOT) return;
  int gc, r; float v;
  if (i < NNZ_W) {
    gc = __builtin_nontemporal_load(&Wc[i]);
    r  = __builtin_nontemporal_load(&Wr[i]);
    v  = __builtin_nontemporal_load(&Wv[i]);
  } else if (i < NNZ_W + NNZ_R) {
    const int j = i - NNZ_W;
    gc = HID + __builtin_nontemporal_load(&Rc[j]);
    r  = __builtin_nontemporal_load(&Rr[j]);
    v  = __builtin_nontemporal_load(&Rv[j]);
  } else {
    const int j = i - NNZ_W - NNZ_R;
    gc = 2 * HID + __builtin_nontemporal_load(&Pc[j]);
    r  = __builtin_nontemporal_load(&Pr[j]);
    v  = __builtin_nontemporal_load(&Pv[j]);
  }
  const int p = atomicAdd(&cnt[gc], 1);
  f2 e; e.x = v; e.y = __int_as_float(r);
  __builtin_nontemporal_store(e, (f2*)&packed[(size_t)gc * SLOT + p]);
}

// ---------------------------------------------------------------------------
// bf16-source column gather, 8 edges in flight.  Meta reads nt (streamed);
// source reads cached (the hot L2 set).
// ---------------------------------------------------------------------------
__device__ __forceinline__ f4 gather_col_bf(const unsigned short* __restrict__ srcb,
                                            const float2* __restrict__ packed,
                                            int gc, int n, int boff, float bias) {
  f4 acc; acc.x = bias; acc.y = bias; acc.z = bias; acc.w = bias;
  const f2* ep = (const f2*)(packed + (size_t)gc * SLOT);
  int i = 0;
  for (; i + 8 <= n; i += 8) {
    f2 e[8]; ushort4_t s[8];
#pragma unroll
    for (int j = 0; j < 8; ++j) e[j] = __builtin_nontemporal_load(ep + i + j);
#pragma unroll
    for (int j = 0; j < 8; ++j)
      s[j] = *(const ushort4_t*)(srcb + (size_t)__float_as_int(e[j].y) * B + boff);
#pragma unroll
    for (int j = 0; j < 8; ++j) {
      acc.x += e[j].x * bf2f(s[j].x);
      acc.y += e[j].x * bf2f(s[j].y);
      acc.z += e[j].x * bf2f(s[j].z);
      acc.w += e[j].x * bf2f(s[j].w);
    }
  }
  for (; i < n; ++i) {
    const f2 e = __builtin_nontemporal_load(ep + i);
    const ushort4_t s = *(const ushort4_t*)(srcb + (size_t)__float_as_int(e.y) * B + boff);
    acc.x += e.x * bf2f(s.x);
    acc.y += e.x * bf2f(s.y);
    acc.z += e.x * bf2f(s.z);
    acc.w += e.x * bf2f(s.w);
  }
  return acc;
}

// XCD-aware decomposition: blk%8 -> XCD (round-robin heuristic).
__device__ __forceinline__ void col_chunk(int blk, int wave, int& c, int& boff, int lane) {
  const int p = blk & 7;
  const int chunk = p >> 2;
  const int cgrp = ((p & 3) << 8) | (blk >> 3);   // 0..1023
  c = cgrp * 4 + wave;
  boff = chunk * 256 + lane * 4;
}

// ---------------------------------------------------------------------------
// Fused: sensory (W,bf16)*mask + recurrent (R,bf16) -> tanh -> integrate.
// hp read nt (touch-once); hnT write nt; hnb write cached (pred's hot source).
// ---------------------------------------------------------------------------
__global__ void fused_gc_k(const unsigned short* __restrict__ xTb,
                           const unsigned short* __restrict__ hTb,
                           const float* __restrict__ hT,
                           const float2* __restrict__ packed, const int* __restrict__ cnt,
                           const float* __restrict__ rgT,
                           const float* __restrict__ gate, const float* __restrict__ tau,
                           const float* __restrict__ wb, const float* __restrict__ rb,
                           float* __restrict__ hnT, unsigned short* __restrict__ hnb) {
  int c, boff;
  col_chunk(blockIdx.x, threadIdx.x >> 6, c, boff, threadIdx.x & 63);

  const f4 sens = gather_col_bf(xTb, packed, c, cnt[c], boff, wb[c]);
  const f4 rec  = gather_col_bf(hTb, packed, HID + c, cnt[HID + c], boff, rb[c]);

  const f4 m  = *(const f4*)(rgT + (size_t)(c >> 6) * B + boff);
  const f4 g  = *(const f4*)(gate + boff);
  const f4 hp = __builtin_nontemporal_load((const f4*)(hT + (size_t)c * B + boff));
  const float k = DT / tau[c];
  f4 hn;
  hn.x = hp.x + g.x * (tanhf(sens.x * m.x + rec.x) - hp.x) * k;
  hn.y = hp.y + g.y * (tanhf(sens.y * m.y + rec.y) - hp.y) * k;
  hn.z = hp.z + g.z * (tanhf(sens.z * m.z + rec.z) - hp.z) * k;
  hn.w = hp.w + g.w * (tanhf(sens.w * m.w + rec.w) - hp.w) * k;
  __builtin_nontemporal_store(hn, (f4*)(hnT + (size_t)c * B + boff));
  ushort4_t hb;
  hb.x = f2bf(hn.x); hb.y = f2bf(hn.y); hb.z = f2bf(hn.z); hb.w = f2bf(hn.w);
  *(ushort4_t*)(hnb + (size_t)c * B + boff) = hb;   // cached
}

// ---------------------------------------------------------------------------
// pred gather (blocks [0,2048)) + out_h transpose (blocks [2048,2560)).
// ---------------------------------------------------------------------------
__global__ void pred_tr_k(const unsigned short* __restrict__ hnb,
                          const float2* __restrict__ packed, const int* __restrict__ cnt,
                          const float* __restrict__ pb, float* __restrict__ predT,
                          const float* __restrict__ hnT, float* __restrict__ out_h) {
  __shared__ float t[64][65];
  const int blk = blockIdx.x;
  if (blk < 2048) {
    int c, boff;
    col_chunk(blk, threadIdx.x >> 6, c, boff, threadIdx.x & 63);
    const f4 p = gather_col_bf(hnb, packed, 2 * HID + c, cnt[2 * HID + c], boff, pb[c]);
    __builtin_nontemporal_store(p, (f4*)(predT + (size_t)c * B + boff));
  } else {
    const int tb = blk - 2048;               // 512 tiles: hnT[HID][B] -> out_h[B][HID]
    const int tx_n = B / 64;
    const int bx = (tb % tx_n) * 64;
    const int by = (tb / tx_n) * 64;
    const int tx = threadIdx.x & 63;
    const int ty = threadIdx.x >> 6;          // 0..3 (256 threads)
    for (int i = ty; i < 64; i += 4)
      t[i][tx] = __builtin_nontemporal_load(&hnT[(size_t)(by + i) * B + bx + tx]);
    __syncthreads();
    for (int i = ty; i < 64; i += 4)
      __builtin_nontemporal_store(t[tx][i], &out_h[(size_t)(bx + i) * HID + by + tx]);
  }
}

// ---------------------------------------------------------------------------
// Final: predT [HID][B] -> out_p [B][HID].
// ---------------------------------------------------------------------------
__global__ void transpose_p_k(const float* __restrict__ predT, float* __restrict__ out_p) {
  __shared__ float t[64][65];
  const int tb = blockIdx.x;
  const int tx_n = B / 64;
  const int bx = (tb % tx_n) * 64;
  const int by = (tb / tx_n) * 64;
  const int tx = threadIdx.x & 63;
  const int ty = threadIdx.x >> 6;            // 0..3
  for (int i = ty; i < 64; i += 4)
    t[i][tx] = __builtin_nontemporal_load(&predT[(size_t)(by + i) * B + bx + tx]);
  __syncthreads();
  for (int i = ty; i < 64; i += 4)
    __builtin_nontemporal_store(t[tx][i], &out_p[(size_t)(bx + i) * HID + by + tx]);
}

}  // namespace

extern "C" void kernel_launch(void* const* d_in, const int* in_sizes, int n_in,
                              void* d_out, int out_size, void* d_ws, size_t ws_size,
                              hipStream_t stream) {
  const float* x        = (const float*)d_in[0];
  const float* h_prev   = (const float*)d_in[1];
  const float* gate     = (const float*)d_in[2];
  const float* W_vals   = (const float*)d_in[3];
  const float* W_bias   = (const float*)d_in[4];
  const float* R_vals   = (const float*)d_in[5];
  const float* R_bias   = (const float*)d_in[6];
  const float* P_vals   = (const float*)d_in[7];
  const float* P_bias   = (const float*)d_in[8];
  const float* router_w = (const float*)d_in[9];
  const float* router_b = (const float*)d_in[10];
  const float* tau      = (const float*)d_in[11];
  const int* W_rows = (const int*)d_in[12];
  const int* W_cols = (const int*)d_in[13];
  const int* R_rows = (const int*)d_in[14];
  const int* R_cols = (const int*)d_in[15];
  const int* P_rows = (const int*)d_in[16];
  const int* P_cols = (const int*)d_in[17];

  float* ws = (float*)d_ws;
  unsigned short* xTb = (unsigned short*)ws;                     // [IN][B]  bf16  2 MB
  float*  hT     = ws + (size_t)IN * B / 2;                      // [HID][B] f32   8 MB
  unsigned short* hTb = (unsigned short*)(hT + (size_t)HID * B); // [HID][B] bf16  4 MB
  float*  rgT    = (float*)(hTb + (size_t)HID * B);              // [64][B]  f32
  float*  hnT    = rgT + 64 * B;                                 // [HID][B] f32   8 MB
  unsigned short* hnb = (unsigned short*)(hnT + (size_t)HID * B);// [HID][B] bf16  4 MB
  float2* packed = (float2*)(hnb + (size_t)HID * B);             // [NCOLS*SLOT]  12.6 MB
  int*    cnt    = (int*)(packed + (size_t)NCOLS * SLOT);        // [NCOLS]
  float*  predT  = ws;   // [HID][B] f32 — reuses xTb+hT region (dead after fused)

  float* out_h = (float*)d_out;
  float* out_p = out_h + (size_t)B * HID;

  // 1. prep: input transposes + router + cnt zeroing.
  prep_k<<<920, 512, 0, stream>>>(x, xTb, h_prev, hT, hTb,
                                  router_w, router_b, rgT, cnt);

  // 2. One-kernel binning into fixed 128-slot column buckets.
  slotscat_k<<<(NTOT + 255) / 256, 256, 0, stream>>>(W_cols, R_cols, P_cols,
                                                     W_rows, R_rows, P_rows,
                                                     W_vals, R_vals, P_vals,
                                                     cnt, packed);

  // 3. Fused sensory+recurrent gather, mask, tanh, integrate (XCD-chunk split).
  fused_gc_k<<<2048, 256, 0, stream>>>(xTb, hTb, hT, packed, cnt, rgT,
                                       gate, tau, W_bias, R_bias, hnT, hnb);

  // 4. Prediction gather + out_h transpose overlapped in one launch.
  pred_tr_k<<<2560, 256, 0, stream>>>(hnb, packed, cnt, P_bias, predT, hnT, out_h);

  // 5. Final small transpose: predT -> out_p.
  transpose_p_k<<<512, 256, 0, stream>>>(predT, out_p);
}

// Round 11
// 117.669 us; speedup vs baseline: 1.1952x; 1.1952x over previous
//
// Round 11: r10 structure with ALL non-temporal hints removed (nt on
// producer->consumer buffers forced ~45MB to HBM round-trips = r10's +26us
// regression).  Keeps merged pred+out_h-transpose launch.
#include <hip/hip_runtime.h>
#include <math.h>

namespace {

constexpr int B     = 512;
constexpr int IN    = 2048;
constexpr int HID   = 4096;
constexpr int NNZ_W = 83886;
constexpr int NNZ_R = 167772;
constexpr int NTOT  = NNZ_W + 2 * NNZ_R;   // 419430 edges across W,R,P
constexpr int NCOLS = 3 * HID;             // global column id = mat*HID + col
constexpr int SLOT  = 128;                 // per-column bucket capacity
constexpr float DT  = 0.1f;

typedef float f4 __attribute__((ext_vector_type(4)));
typedef float f2 __attribute__((ext_vector_type(2)));

struct ushort4_t { unsigned short x, y, z, w; };

__device__ __forceinline__ float bf2f(unsigned short u) {
  return __uint_as_float((unsigned int)u << 16);
}
__device__ __forceinline__ unsigned short f2bf(float f) {  // round-nearest-even
  unsigned int u = __float_as_uint(f);
  u += 0x7FFFu + ((u >> 16) & 1u);
  return (unsigned short)(u >> 16);
}

// ---------------------------------------------------------------------------
// prep_k, 512 threads, multi-role by blockIdx.x:
//  [0,256)    transpose x[B][IN]  -> xTb (bf16) [IN][B]
//  [256,768)  transpose h[B][HID] -> hT (f32) + hTb (bf16) [HID][B]
//  [768,896)  router: 4 batch rows per block, wave-per-output
//  [896,920)  zero cnt[NCOLS]
// ---------------------------------------------------------------------------
__global__ void prep_k(const float* __restrict__ x, unsigned short* __restrict__ xTb,
                       const float* __restrict__ h, float* __restrict__ hT,
                       unsigned short* __restrict__ hTb,
                       const float* __restrict__ rw, const float* __restrict__ rb,
                       float* __restrict__ rgT, int* __restrict__ cnt) {
  __shared__ float sh[4 * IN];            // 32 KB; transpose uses first 4160
  const int blk = blockIdx.x;
  const int tid = threadIdx.x;

  if (blk < 768) {                        // --- transpose roles ---
    const bool isX = blk < 256;
    const float* src; int C, tb;
    if (isX) { src = x; C = IN;  tb = blk; }
    else     { src = h; C = HID; tb = blk - 256; }
    const int tx_n = C / 64;
    const int bx = (tb % tx_n) * 64;
    const int by = (tb / tx_n) * 64;
    const int tx = tid & 63;
    const int ty = tid >> 6;              // 0..7
    for (int i = ty; i < 64; i += 8)
      sh[i * 65 + tx] = src[(size_t)(by + i) * C + bx + tx];
    __syncthreads();
    for (int i = ty; i < 64; i += 8) {
      const float v = sh[tx * 65 + i];
      const size_t di = (size_t)(bx + i) * B + by + tx;
      if (isX) xTb[di] = f2bf(v);
      else     { hT[di] = v; hTb[di] = f2bf(v); }
    }
  } else if (blk < 896) {                 // --- router: 4 b-rows per block ---
    const int b0 = (blk - 768) * 4;
    for (int k = tid; k < 4 * IN; k += 512) sh[k] = x[(size_t)b0 * IN + k];
    __syncthreads();
    const int wave = tid >> 6;
    const int lane = tid & 63;
#pragma unroll
    for (int j = 0; j < 8; ++j) {
      const int o = wave * 8 + j;
      const float* w = rw + (size_t)o * IN;
      float s0 = 0.f, s1 = 0.f, s2 = 0.f, s3 = 0.f;
      for (int i = 0; i < IN / 64; ++i) {           // 32 iters
        const float wv = w[lane + 64 * i];          // coalesced 256B
        s0 += sh[0 * IN + lane + 64 * i] * wv;
        s1 += sh[1 * IN + lane + 64 * i] * wv;
        s2 += sh[2 * IN + lane + 64 * i] * wv;
        s3 += sh[3 * IN + lane + 64 * i] * wv;
      }
#pragma unroll
      for (int d = 1; d < 64; d <<= 1) {
        s0 += __shfl_xor(s0, d);
        s1 += __shfl_xor(s1, d);
        s2 += __shfl_xor(s2, d);
        s3 += __shfl_xor(s3, d);
      }
      if (lane == 0) {
        const float bias = rb[o];
        rgT[o * B + b0 + 0] = 1.f / (1.f + expf(-(s0 + bias)));
        rgT[o * B + b0 + 1] = 1.f / (1.f + expf(-(s1 + bias)));
        rgT[o * B + b0 + 2] = 1.f / (1.f + expf(-(s2 + bias)));
        rgT[o * B + b0 + 3] = 1.f / (1.f + expf(-(s3 + bias)));
      }
    }
  } else {                                // --- zero cnt ---
    const int i = (blk - 896) * 512 + tid;
    if (i < NCOLS) cnt[i] = 0;
  }
}

// ---------------------------------------------------------------------------
// One-kernel binning: edge -> (global col bucket, atomic slot).
// ---------------------------------------------------------------------------
__global__ void slotscat_k(const int* __restrict__ Wc, const int* __restrict__ Rc,
                           const int* __restrict__ Pc, const int* __restrict__ Wr,
                           const int* __restrict__ Rr, const int* __restrict__ Pr,
                           const float* __restrict__ Wv, const float* __restrict__ Rv,
                           const float* __restrict__ Pv, int* __restrict__ cnt,
                           float2* __restrict__ packed) {
  const int i = blockIdx.x * blockDim.x + threadIdx.x;
  if (i >= NTOT) return;
  int gc, r; float v;
  if (i < NNZ_W)              { gc = Wc[i];                 r = Wr[i]; v = Wv[i]; }
  else if (i < NNZ_W + NNZ_R) { int j = i - NNZ_W;          gc = HID + Rc[j];     r = Rr[j]; v = Rv[j]; }
  else                        { int j = i - NNZ_W - NNZ_R; gc = 2 * HID + Pc[j]; r = Pr[j]; v = Pv[j]; }
  const int p = atomicAdd(&cnt[gc], 1);
  packed[(size_t)gc * SLOT + p] = make_float2(v, __int_as_float(r));
}

// ---------------------------------------------------------------------------
// bf16-source column gather, 8 edges in flight (all cached).
// ---------------------------------------------------------------------------
__device__ __forceinline__ f4 gather_col_bf(const unsigned short* __restrict__ srcb,
                                            const float2* __restrict__ packed,
                                            int gc, int n, int boff, float bias) {
  f4 acc; acc.x = bias; acc.y = bias; acc.z = bias; acc.w = bias;
  const f2* ep = (const f2*)(packed + (size_t)gc * SLOT);
  int i = 0;
  for (; i + 8 <= n; i += 8) {
    f2 e[8]; ushort4_t s[8];
#pragma unroll
    for (int j = 0; j < 8; ++j) e[j] = ep[i + j];
#pragma unroll
    for (int j = 0; j < 8; ++j)
      s[j] = *(const ushort4_t*)(srcb + (size_t)__float_as_int(e[j].y) * B + boff);
#pragma unroll
    for (int j = 0; j < 8; ++j) {
      acc.x += e[j].x * bf2f(s[j].x);
      acc.y += e[j].x * bf2f(s[j].y);
      acc.z += e[j].x * bf2f(s[j].z);
      acc.w += e[j].x * bf2f(s[j].w);
    }
  }
  for (; i < n; ++i) {
    const f2 e = ep[i];
    const ushort4_t s = *(const ushort4_t*)(srcb + (size_t)__float_as_int(e.y) * B + boff);
    acc.x += e.x * bf2f(s.x);
    acc.y += e.x * bf2f(s.y);
    acc.z += e.x * bf2f(s.z);
    acc.w += e.x * bf2f(s.w);
  }
  return acc;
}

// XCD-aware decomposition: blk%8 -> XCD (round-robin heuristic).
__device__ __forceinline__ void col_chunk(int blk, int wave, int& c, int& boff, int lane) {
  const int p = blk & 7;
  const int chunk = p >> 2;
  const int cgrp = ((p & 3) << 8) | (blk >> 3);   // 0..1023
  c = cgrp * 4 + wave;
  boff = chunk * 256 + lane * 4;
}

// ---------------------------------------------------------------------------
// Fused: sensory (W,bf16)*mask + recurrent (R,bf16) -> tanh -> integrate.
// ---------------------------------------------------------------------------
__global__ void fused_gc_k(const unsigned short* __restrict__ xTb,
                           const unsigned short* __restrict__ hTb,
                           const float* __restrict__ hT,
                           const float2* __restrict__ packed, const int* __restrict__ cnt,
                           const float* __restrict__ rgT,
                           const float* __restrict__ gate, const float* __restrict__ tau,
                           const float* __restrict__ wb, const float* __restrict__ rb,
                           float* __restrict__ hnT, unsigned short* __restrict__ hnb) {
  int c, boff;
  col_chunk(blockIdx.x, threadIdx.x >> 6, c, boff, threadIdx.x & 63);

  const f4 sens = gather_col_bf(xTb, packed, c, cnt[c], boff, wb[c]);
  const f4 rec  = gather_col_bf(hTb, packed, HID + c, cnt[HID + c], boff, rb[c]);

  const f4 m  = *(const f4*)(rgT + (size_t)(c >> 6) * B + boff);
  const f4 g  = *(const f4*)(gate + boff);
  const f4 hp = *(const f4*)(hT + (size_t)c * B + boff);
  const float k = DT / tau[c];
  f4 hn;
  hn.x = hp.x + g.x * (tanhf(sens.x * m.x + rec.x) - hp.x) * k;
  hn.y = hp.y + g.y * (tanhf(sens.y * m.y + rec.y) - hp.y) * k;
  hn.z = hp.z + g.z * (tanhf(sens.z * m.z + rec.z) - hp.z) * k;
  hn.w = hp.w + g.w * (tanhf(sens.w * m.w + rec.w) - hp.w) * k;
  *(f4*)(hnT + (size_t)c * B + boff) = hn;
  ushort4_t hb;
  hb.x = f2bf(hn.x); hb.y = f2bf(hn.y); hb.z = f2bf(hn.z); hb.w = f2bf(hn.w);
  *(ushort4_t*)(hnb + (size_t)c * B + boff) = hb;
}

// ---------------------------------------------------------------------------
// pred gather (blocks [0,2048)) + out_h transpose (blocks [2048,2560)).
// ---------------------------------------------------------------------------
__global__ void pred_tr_k(const unsigned short* __restrict__ hnb,
                          const float2* __restrict__ packed, const int* __restrict__ cnt,
                          const float* __restrict__ pb, float* __restrict__ predT,
                          const float* __restrict__ hnT, float* __restrict__ out_h) {
  __shared__ float t[64][65];
  const int blk = blockIdx.x;
  if (blk < 2048) {
    int c, boff;
    col_chunk(blk, threadIdx.x >> 6, c, boff, threadIdx.x & 63);
    const f4 p = gather_col_bf(hnb, packed, 2 * HID + c, cnt[2 * HID + c], boff, pb[c]);
    *(f4*)(predT + (size_t)c * B + boff) = p;
  } else {
    const int tb = blk - 2048;               // 512 tiles: hnT[HID][B] -> out_h[B][HID]
    const int tx_n = B / 64;
    const int bx = (tb % tx_n) * 64;
    const int by = (tb / tx_n) * 64;
    const int tx = threadIdx.x & 63;
    const int ty = threadIdx.x >> 6;          // 0..3 (256 threads)
    for (int i = ty; i < 64; i += 4)
      t[i][tx] = hnT[(size_t)(by + i) * B + bx + tx];
    __syncthreads();
    for (int i = ty; i < 64; i += 4)
      out_h[(size_t)(bx + i) * HID + by + tx] = t[tx][i];
  }
}

// ---------------------------------------------------------------------------
// Final: predT [HID][B] -> out_p [B][HID].
// ---------------------------------------------------------------------------
__global__ void transpose_p_k(const float* __restrict__ predT, float* __restrict__ out_p) {
  __shared__ float t[64][65];
  const int tb = blockIdx.x;
  const int tx_n = B / 64;
  const int bx = (tb % tx_n) * 64;
  const int by = (tb / tx_n) * 64;
  const int tx = threadIdx.x & 63;
  const int ty = threadIdx.x >> 6;            // 0..3
  for (int i = ty; i < 64; i += 4)
    t[i][tx] = predT[(size_t)(by + i) * B + bx + tx];
  __syncthreads();
  for (int i = ty; i < 64; i += 4)
    out_p[(size_t)(bx + i) * HID + by + tx] = t[tx][i];
}

}  // namespace

extern "C" void kernel_launch(void* const* d_in, const int* in_sizes, int n_in,
                              void* d_out, int out_size, void* d_ws, size_t ws_size,
                              hipStream_t stream) {
  const float* x        = (const float*)d_in[0];
  const float* h_prev   = (const float*)d_in[1];
  const float* gate     = (const float*)d_in[2];
  const float* W_vals   = (const float*)d_in[3];
  const float* W_bias   = (const float*)d_in[4];
  const float* R_vals   = (const float*)d_in[5];
  const float* R_bias   = (const float*)d_in[6];
  const float* P_vals   = (const float*)d_in[7];
  const float* P_bias   = (const float*)d_in[8];
  const float* router_w = (const float*)d_in[9];
  const float* router_b = (const float*)d_in[10];
  const float* tau      = (const float*)d_in[11];
  const int* W_rows = (const int*)d_in[12];
  const int* W_cols = (const int*)d_in[13];
  const int* R_rows = (const int*)d_in[14];
  const int* R_cols = (const int*)d_in[15];
  const int* P_rows = (const int*)d_in[16];
  const int* P_cols = (const int*)d_in[17];

  float* ws = (float*)d_ws;
  unsigned short* xTb = (unsigned short*)ws;                     // [IN][B]  bf16  2 MB
  float*  hT     = ws + (size_t)IN * B / 2;                      // [HID][B] f32   8 MB
  unsigned short* hTb = (unsigned short*)(hT + (size_t)HID * B); // [HID][B] bf16  4 MB
  float*  rgT    = (float*)(hTb + (size_t)HID * B);              // [64][B]  f32
  float*  hnT    = rgT + 64 * B;                                 // [HID][B] f32   8 MB
  unsigned short* hnb = (unsigned short*)(hnT + (size_t)HID * B);// [HID][B] bf16  4 MB
  float2* packed = (float2*)(hnb + (size_t)HID * B);             // [NCOLS*SLOT]  12.6 MB
  int*    cnt    = (int*)(packed + (size_t)NCOLS * SLOT);        // [NCOLS]
  float*  predT  = ws;   // [HID][B] f32 — reuses xTb+hT region (dead after fused)

  float* out_h = (float*)d_out;
  float* out_p = out_h + (size_t)B * HID;

  // 1. prep: input transposes + router + cnt zeroing.
  prep_k<<<920, 512, 0, stream>>>(x, xTb, h_prev, hT, hTb,
                                  router_w, router_b, rgT, cnt);

  // 2. One-kernel binning into fixed 128-slot column buckets.
  slotscat_k<<<(NTOT + 255) / 256, 256, 0, stream>>>(W_cols, R_cols, P_cols,
                                                     W_rows, R_rows, P_rows,
                                                     W_vals, R_vals, P_vals,
                                                     cnt, packed);

  // 3. Fused sensory+recurrent gather, mask, tanh, integrate (XCD-chunk split).
  fused_gc_k<<<2048, 256, 0, stream>>>(xTb, hTb, hT, packed, cnt, rgT,
                                       gate, tau, W_bias, R_bias, hnT, hnb);

  // 4. Prediction gather + out_h transpose overlapped in one launch.
  pred_tr_k<<<2560, 256, 0, stream>>>(hnb, packed, cnt, P_bias, predT, hnT, out_h);

  // 5. Final small transpose: predT -> out_p.
  transpose_p_k<<<512, 256, 0, stream>>>(predT, out_p);
}

// Round 12
// 111.851 us; speedup vs baseline: 1.2574x; 1.0520x over previous
//
// Round 12: direct transposed output writes from the gather kernels (LDS 4KB
// per-block tile transpose) — eliminates hnT/predT round-trips (32MB of L2
// traffic) and the final transpose dispatch.  4-kernel pipeline.
#include <hip/hip_runtime.h>
#include <math.h>

namespace {

constexpr int B     = 512;
constexpr int IN    = 2048;
constexpr int HID   = 4096;
constexpr int NNZ_W = 83886;
constexpr int NNZ_R = 167772;
constexpr int NTOT  = NNZ_W + 2 * NNZ_R;   // 419430 edges across W,R,P
constexpr int NCOLS = 3 * HID;             // global column id = mat*HID + col
constexpr int SLOT  = 128;                 // per-column bucket capacity
constexpr float DT  = 0.1f;

typedef float f4 __attribute__((ext_vector_type(4)));
typedef float f2 __attribute__((ext_vector_type(2)));

struct ushort4_t { unsigned short x, y, z, w; };

__device__ __forceinline__ float bf2f(unsigned short u) {
  return __uint_as_float((unsigned int)u << 16);
}
__device__ __forceinline__ unsigned short f2bf(float f) {  // round-nearest-even
  unsigned int u = __float_as_uint(f);
  u += 0x7FFFu + ((u >> 16) & 1u);
  return (unsigned short)(u >> 16);
}

// ---------------------------------------------------------------------------
// prep_k, 512 threads, multi-role by blockIdx.x:
//  [0,256)    transpose x[B][IN]  -> xTb (bf16) [IN][B]
//  [256,768)  transpose h[B][HID] -> hT (f32) + hTb (bf16) [HID][B]
//  [768,896)  router: 4 batch rows per block, wave-per-output
//  [896,920)  zero cnt[NCOLS]
// ---------------------------------------------------------------------------
__global__ void prep_k(const float* __restrict__ x, unsigned short* __restrict__ xTb,
                       const float* __restrict__ h, float* __restrict__ hT,
                       unsigned short* __restrict__ hTb,
                       const float* __restrict__ rw, const float* __restrict__ rb,
                       float* __restrict__ rgT, int* __restrict__ cnt) {
  __shared__ float sh[4 * IN];            // 32 KB; transpose uses first 4160
  const int blk = blockIdx.x;
  const int tid = threadIdx.x;

  if (blk < 768) {                        // --- transpose roles ---
    const bool isX = blk < 256;
    const float* src; int C, tb;
    if (isX) { src = x; C = IN;  tb = blk; }
    else     { src = h; C = HID; tb = blk - 256; }
    const int tx_n = C / 64;
    const int bx = (tb % tx_n) * 64;
    const int by = (tb / tx_n) * 64;
    const int tx = tid & 63;
    const int ty = tid >> 6;              // 0..7
    for (int i = ty; i < 64; i += 8)
      sh[i * 65 + tx] = src[(size_t)(by + i) * C + bx + tx];
    __syncthreads();
    for (int i = ty; i < 64; i += 8) {
      const float v = sh[tx * 65 + i];
      const size_t di = (size_t)(bx + i) * B + by + tx;
      if (isX) xTb[di] = f2bf(v);
      else     { hT[di] = v; hTb[di] = f2bf(v); }
    }
  } else if (blk < 896) {                 // --- router: 4 b-rows per block ---
    const int b0 = (blk - 768) * 4;
    for (int k = tid; k < 4 * IN; k += 512) sh[k] = x[(size_t)b0 * IN + k];
    __syncthreads();
    const int wave = tid >> 6;
    const int lane = tid & 63;
#pragma unroll
    for (int j = 0; j < 8; ++j) {
      const int o = wave * 8 + j;
      const float* w = rw + (size_t)o * IN;
      float s0 = 0.f, s1 = 0.f, s2 = 0.f, s3 = 0.f;
      for (int i = 0; i < IN / 64; ++i) {           // 32 iters
        const float wv = w[lane + 64 * i];          // coalesced 256B
        s0 += sh[0 * IN + lane + 64 * i] * wv;
        s1 += sh[1 * IN + lane + 64 * i] * wv;
        s2 += sh[2 * IN + lane + 64 * i] * wv;
        s3 += sh[3 * IN + lane + 64 * i] * wv;
      }
#pragma unroll
      for (int d = 1; d < 64; d <<= 1) {
        s0 += __shfl_xor(s0, d);
        s1 += __shfl_xor(s1, d);
        s2 += __shfl_xor(s2, d);
        s3 += __shfl_xor(s3, d);
      }
      if (lane == 0) {
        const float bias = rb[o];
        rgT[o * B + b0 + 0] = 1.f / (1.f + expf(-(s0 + bias)));
        rgT[o * B + b0 + 1] = 1.f / (1.f + expf(-(s1 + bias)));
        rgT[o * B + b0 + 2] = 1.f / (1.f + expf(-(s2 + bias)));
        rgT[o * B + b0 + 3] = 1.f / (1.f + expf(-(s3 + bias)));
      }
    }
  } else {                                // --- zero cnt ---
    const int i = (blk - 896) * 512 + tid;
    if (i < NCOLS) cnt[i] = 0;
  }
}

// ---------------------------------------------------------------------------
// One-kernel binning: edge -> (global col bucket, atomic slot).
// ---------------------------------------------------------------------------
__global__ void slotscat_k(const int* __restrict__ Wc, const int* __restrict__ Rc,
                           const int* __restrict__ Pc, const int* __restrict__ Wr,
                           const int* __restrict__ Rr, const int* __restrict__ Pr,
                           const float* __restrict__ Wv, const float* __restrict__ Rv,
                           const float* __restrict__ Pv, int* __restrict__ cnt,
                           float2* __restrict__ packed) {
  const int i = blockIdx.x * blockDim.x + threadIdx.x;
  if (i >= NTOT) return;
  int gc, r; float v;
  if (i < NNZ_W)              { gc = Wc[i];                 r = Wr[i]; v = Wv[i]; }
  else if (i < NNZ_W + NNZ_R) { int j = i - NNZ_W;          gc = HID + Rc[j];     r = Rr[j]; v = Rv[j]; }
  else                        { int j = i - NNZ_W - NNZ_R; gc = 2 * HID + Pc[j]; r = Pr[j]; v = Pv[j]; }
  const int p = atomicAdd(&cnt[gc], 1);
  packed[(size_t)gc * SLOT + p] = make_float2(v, __int_as_float(r));
}

// ---------------------------------------------------------------------------
// bf16-source column gather, 8 edges in flight (all cached).
// ---------------------------------------------------------------------------
__device__ __forceinline__ f4 gather_col_bf(const unsigned short* __restrict__ srcb,
                                            const float2* __restrict__ packed,
                                            int gc, int n, int boff, float bias) {
  f4 acc; acc.x = bias; acc.y = bias; acc.z = bias; acc.w = bias;
  const f2* ep = (const f2*)(packed + (size_t)gc * SLOT);
  int i = 0;
  for (; i + 8 <= n; i += 8) {
    f2 e[8]; ushort4_t s[8];
#pragma unroll
    for (int j = 0; j < 8; ++j) e[j] = ep[i + j];
#pragma unroll
    for (int j = 0; j < 8; ++j)
      s[j] = *(const ushort4_t*)(srcb + (size_t)__float_as_int(e[j].y) * B + boff);
#pragma unroll
    for (int j = 0; j < 8; ++j) {
      acc.x += e[j].x * bf2f(s[j].x);
      acc.y += e[j].x * bf2f(s[j].y);
      acc.z += e[j].x * bf2f(s[j].z);
      acc.w += e[j].x * bf2f(s[j].w);
    }
  }
  for (; i < n; ++i) {
    const f2 e = ep[i];
    const ushort4_t s = *(const ushort4_t*)(srcb + (size_t)__float_as_int(e.y) * B + boff);
    acc.x += e.x * bf2f(s.x);
    acc.y += e.x * bf2f(s.y);
    acc.z += e.x * bf2f(s.z);
    acc.w += e.x * bf2f(s.w);
  }
  return acc;
}

// XCD-aware decomposition: blk%8 -> XCD (round-robin heuristic).
// Block covers columns c0..c0+3 (c0 = cgrp*4, wave w owns c0+w) and batch
// rows chunk*256..chunk*256+255 (lane owns 4 consecutive b).
__device__ __forceinline__ void col_chunk(int blk, int wave, int& c, int& boff,
                                          int lane, int& cgrp, int& chunk) {
  const int p = blk & 7;
  chunk = p >> 2;
  cgrp = ((p & 3) << 8) | (blk >> 3);   // 0..1023
  c = cgrp * 4 + wave;
  boff = chunk * 256 + lane * 4;
}

// Shared epilogue: transpose the block's [256 b][4 c] tile in LDS and store
// one f4 row-major output row-fragment per thread.
__device__ __forceinline__ void store_tile_T(float* __restrict__ tile,  // [4][256]
                                             const f4 v, int wave, int lane,
                                             int cgrp, int chunk,
                                             float* __restrict__ out) {
  ((f4*)tile)[wave * 64 + lane] = v;      // conflict-free b128 writes
  __syncthreads();
  const int t = threadIdx.x;              // 0..255 = local b
  f4 o;
  o.x = tile[0 * 256 + t];
  o.y = tile[1 * 256 + t];
  o.z = tile[2 * 256 + t];
  o.w = tile[3 * 256 + t];
  *(f4*)(out + (size_t)(chunk * 256 + t) * HID + cgrp * 4) = o;
}

// ---------------------------------------------------------------------------
// Fused: sensory (W,bf16)*mask + recurrent (R,bf16) -> tanh -> integrate.
// Writes out_h DIRECTLY (LDS tile transpose) + hnb (bf16, pred's source).
// ---------------------------------------------------------------------------
__global__ void fused_gc_k(const unsigned short* __restrict__ xTb,
                           const unsigned short* __restrict__ hTb,
                           const float* __restrict__ hT,
                           const float2* __restrict__ packed, const int* __restrict__ cnt,
                           const float* __restrict__ rgT,
                           const float* __restrict__ gate, const float* __restrict__ tau,
                           const float* __restrict__ wb, const float* __restrict__ rb,
                           float* __restrict__ out_h, unsigned short* __restrict__ hnb) {
  __shared__ float tile[4 * 256];
  int c, boff, cgrp, chunk;
  const int wave = threadIdx.x >> 6, lane = threadIdx.x & 63;
  col_chunk(blockIdx.x, wave, c, boff, lane, cgrp, chunk);

  const f4 sens = gather_col_bf(xTb, packed, c, cnt[c], boff, wb[c]);
  const f4 rec  = gather_col_bf(hTb, packed, HID + c, cnt[HID + c], boff, rb[c]);

  const f4 m  = *(const f4*)(rgT + (size_t)(c >> 6) * B + boff);
  const f4 g  = *(const f4*)(gate + boff);
  const f4 hp = *(const f4*)(hT + (size_t)c * B + boff);
  const float k = DT / tau[c];
  f4 hn;
  hn.x = hp.x + g.x * (tanhf(sens.x * m.x + rec.x) - hp.x) * k;
  hn.y = hp.y + g.y * (tanhf(sens.y * m.y + rec.y) - hp.y) * k;
  hn.z = hp.z + g.z * (tanhf(sens.z * m.z + rec.z) - hp.z) * k;
  hn.w = hp.w + g.w * (tanhf(sens.w * m.w + rec.w) - hp.w) * k;

  ushort4_t hb;
  hb.x = f2bf(hn.x); hb.y = f2bf(hn.y); hb.z = f2bf(hn.z); hb.w = f2bf(hn.w);
  *(ushort4_t*)(hnb + (size_t)c * B + boff) = hb;   // cached: pred's hot source

  store_tile_T(tile, hn, wave, lane, cgrp, chunk, out_h);
}

// ---------------------------------------------------------------------------
// Prediction gather from h_new (bf16), writes out_p DIRECTLY.
// ---------------------------------------------------------------------------
__global__ void pred_k(const unsigned short* __restrict__ hnb,
                       const float2* __restrict__ packed, const int* __restrict__ cnt,
                       const float* __restrict__ pb, float* __restrict__ out_p) {
  __shared__ float tile[4 * 256];
  int c, boff, cgrp, chunk;
  const int wave = threadIdx.x >> 6, lane = threadIdx.x & 63;
  col_chunk(blockIdx.x, wave, c, boff, lane, cgrp, chunk);
  const f4 p = gather_col_bf(hnb, packed, 2 * HID + c, cnt[2 * HID + c], boff, pb[c]);
  store_tile_T(tile, p, wave, lane, cgrp, chunk, out_p);
}

}  // namespace

extern "C" void kernel_launch(void* const* d_in, const int* in_sizes, int n_in,
                              void* d_out, int out_size, void* d_ws, size_t ws_size,
                              hipStream_t stream) {
  const float* x        = (const float*)d_in[0];
  const float* h_prev   = (const float*)d_in[1];
  const float* gate     = (const float*)d_in[2];
  const float* W_vals   = (const float*)d_in[3];
  const float* W_bias   = (const float*)d_in[4];
  const float* R_vals   = (const float*)d_in[5];
  const float* R_bias   = (const float*)d_in[6];
  const float* P_vals   = (const float*)d_in[7];
  const float* P_bias   = (const float*)d_in[8];
  const float* router_w = (const float*)d_in[9];
  const float* router_b = (const float*)d_in[10];
  const float* tau      = (const float*)d_in[11];
  const int* W_rows = (const int*)d_in[12];
  const int* W_cols = (const int*)d_in[13];
  const int* R_rows = (const int*)d_in[14];
  const int* R_cols = (const int*)d_in[15];
  const int* P_rows = (const int*)d_in[16];
  const int* P_cols = (const int*)d_in[17];

  float* ws = (float*)d_ws;
  unsigned short* xTb = (unsigned short*)ws;                     // [IN][B]  bf16  2 MB
  float*  hT     = ws + (size_t)IN * B / 2;                      // [HID][B] f32   8 MB
  unsigned short* hTb = (unsigned short*)(hT + (size_t)HID * B); // [HID][B] bf16  4 MB
  float*  rgT    = (float*)(hTb + (size_t)HID * B);              // [64][B]  f32
  unsigned short* hnb = (unsigned short*)(rgT + 64 * B);         // [HID][B] bf16  4 MB
  float2* packed = (float2*)(hnb + (size_t)HID * B);             // [NCOLS*SLOT]  12.6 MB
  int*    cnt    = (int*)(packed + (size_t)NCOLS * SLOT);        // [NCOLS]

  float* out_h = (float*)d_out;
  float* out_p = out_h + (size_t)B * HID;

  // 1. prep: input transposes + router + cnt zeroing.
  prep_k<<<920, 512, 0, stream>>>(x, xTb, h_prev, hT, hTb,
                                  router_w, router_b, rgT, cnt);

  // 2. One-kernel binning into fixed 128-slot column buckets.
  slotscat_k<<<(NTOT + 255) / 256, 256, 0, stream>>>(W_cols, R_cols, P_cols,
                                                     W_rows, R_rows, P_rows,
                                                     W_vals, R_vals, P_vals,
                                                     cnt, packed);

  // 3. Fused gather + integrate -> out_h (direct) + hnb.
  fused_gc_k<<<2048, 256, 0, stream>>>(xTb, hTb, hT, packed, cnt, rgT,
                                       gate, tau, W_bias, R_bias, out_h, hnb);

  // 4. Prediction gather -> out_p (direct).
  pred_k<<<2048, 256, 0, stream>>>(hnb, packed, cnt, P_bias, out_p);
}